// Round 2
// baseline (1211.095 us; speedup 1.0000x reference)
//
#include <hip/hip_runtime.h>
#include <hip/hip_bf16.h>

// Problem constants (from reference)
#define E_   8
#define D_   1024
#define H_   4096
#define T_   8192      // B*S tokens
#define TM   128       // GEMM M/N tile
#define BK   64        // GEMM K chunk (bf16)
#define CAP  17408     // 136*128 >= 16384 + 8*127 padded capacity
#define NBY  136       // CAP/TM
#define SPLITK 4       // fc2 K-split (K=4096 -> 4 x 1024)

typedef __attribute__((ext_vector_type(8))) short short8;   // 8 bf16 = 4 VGPRs (MFMA A/B frag)
typedef __attribute__((ext_vector_type(4))) float floatx4;  // MFMA C/D frag

__device__ __forceinline__ unsigned short f2bf(float f) {
    unsigned u = __float_as_uint(f);
    u += 0x7fffu + ((u >> 16) & 1u);   // RNE truncate to bf16
    return (unsigned short)(u >> 16);
}

// direct global->LDS async copy, 16B/lane; lds base must be wave-uniform
#define GLP16(g, l)                                                             \
    __builtin_amdgcn_global_load_lds((const __attribute__((address_space(1))) void*)(g), \
                                     (__attribute__((address_space(3))) void*)(l), 16, 0, 0)

// ---------------- Router: 1 wave per token ----------------
__global__ __launch_bounds__(64) void router_kernel(
    const float* __restrict__ x, const float* __restrict__ Wr,
    int* __restrict__ cnt, int* __restrict__ tok_list, float* __restrict__ w_list)
{
    int t = blockIdx.x;
    int lane = threadIdx.x;
    const float* xr = x + (size_t)t * D_;
    float acc[E_];
#pragma unroll
    for (int e = 0; e < E_; ++e) acc[e] = 0.f;
    for (int it = 0; it < D_ / 64; ++it) {
        float xv = xr[lane + it * 64];
#pragma unroll
        for (int e = 0; e < E_; ++e) acc[e] += xv * Wr[e * D_ + lane + it * 64];
    }
#pragma unroll
    for (int e = 0; e < E_; ++e) {
#pragma unroll
        for (int off = 32; off; off >>= 1) acc[e] += __shfl_xor(acc[e], off);
    }
    if (lane == 0) {
        float m = acc[0];
#pragma unroll
        for (int e = 1; e < E_; ++e) m = fmaxf(m, acc[e]);
        float p[E_]; float s = 0.f;
#pragma unroll
        for (int e = 0; e < E_; ++e) { p[e] = expf(acc[e] - m); s += p[e]; }
        float inv = 1.f / s;
        int i1 = 0; float v1 = p[0];
#pragma unroll
        for (int e = 1; e < E_; ++e) if (p[e] > v1) { v1 = p[e]; i1 = e; }
        int i2 = -1; float v2 = -1.f;
#pragma unroll
        for (int e = 0; e < E_; ++e) { if (e == i1) continue; if (p[e] > v2) { v2 = p[e]; i2 = e; } }
        v1 *= inv; v2 *= inv;
        int pos1 = atomicAdd(&cnt[i1], 1);
        tok_list[i1 * T_ + pos1] = t; w_list[i1 * T_ + pos1] = v1;
        int pos2 = atomicAdd(&cnt[i2], 1);
        tok_list[i2 * T_ + pos2] = t; w_list[i2 * T_ + pos2] = v2;
    }
}

// ---------------- Prefix: 128-aligned expert regions ----------------
__global__ void offsets_kernel(const int* __restrict__ cnt, int* __restrict__ start)
{
    if (threadIdx.x == 0) {
        int s = 0;
        for (int e = 0; e < E_; ++e) {
            start[e] = s;
            s += (cnt[e] + TM - 1) / TM * TM;
        }
        start[E_] = s;
    }
}

// ---------------- Gather x rows -> bf16, record token/weight ----------------
__global__ __launch_bounds__(256) void gather_kernel(
    const float* __restrict__ x, const int* __restrict__ cnt, const int* __restrict__ start,
    const int* __restrict__ tok_list, const float* __restrict__ w_list,
    unsigned short* __restrict__ xg, int* __restrict__ tok, float* __restrict__ wgt)
{
    int row = blockIdx.x;
    int tid = threadIdx.x;
    int tot = start[E_];
    if (row >= tot) {
        if (tid == 0) { tok[row] = -1; wgt[row] = 0.f; }
        return;
    }
    int e = 0;
    while (e < E_ - 1 && row >= start[e + 1]) ++e;
    int idx = row - start[e];
    unsigned short* dst = xg + (size_t)row * D_;
    if (idx < cnt[e]) {
        int t = tok_list[e * T_ + idx];
        if (tid == 0) { tok[row] = t; wgt[row] = w_list[e * T_ + idx]; }
        const float4* src = (const float4*)(x + (size_t)t * D_);
        float4 v = src[tid];
        ushort4 o; o.x = f2bf(v.x); o.y = f2bf(v.y); o.z = f2bf(v.z); o.w = f2bf(v.w);
        ((ushort4*)dst)[tid] = o;
    } else {
        if (tid == 0) { tok[row] = -1; wgt[row] = 0.f; }
        ((ushort4*)dst)[tid] = make_ushort4(0, 0, 0, 0);  // zero pad rows
    }
}

// ---------------- Transpose + fp32->bf16: in[E][R][C] -> out[E][C][R] ----------------
__global__ __launch_bounds__(256) void transpose_cvt(
    const float* __restrict__ in, unsigned short* __restrict__ out, int R, int C)
{
    __shared__ float tile[32][33];
    int e = blockIdx.z;
    int c0 = blockIdx.x * 32, r0 = blockIdx.y * 32;
    const float* src = in + (size_t)e * R * C;
    unsigned short* dst = out + (size_t)e * R * C;
    int tx = threadIdx.x & 31, ty = threadIdx.x >> 5;
#pragma unroll
    for (int i = 0; i < 32; i += 8)
        tile[ty + i][tx] = src[(size_t)(r0 + ty + i) * C + c0 + tx];
    __syncthreads();
#pragma unroll
    for (int i = 0; i < 32; i += 8)
        dst[(size_t)(c0 + ty + i) * R + r0 + tx] = f2bf(tile[tx][ty + i]);
}

// ---------------- fc1: h = gelu(Xg @ W1 + b1), bf16 out ----------------
// Xg: [CAP][D_] bf16 row-major. W1t: [E][H_][D_] bf16 (B^T). h: [CAP][H_] bf16.
// LDS layout XOR-swizzled: LDS(row, cg) holds global(row, cg ^ (row&7)),
// cg = 16B column group. Staging permutes lanes within a row (coalescing kept);
// readers XOR the group index -> 16 lanes spread over all 32 banks (2-way, free).
__global__ __launch_bounds__(256) void fc1_kernel(
    const unsigned short* __restrict__ xg, const unsigned short* __restrict__ w1t,
    const float* __restrict__ b1, const int* __restrict__ start, unsigned short* __restrict__ h)
{
    __shared__ __align__(16) unsigned short Asm[TM * BK];
    __shared__ __align__(16) unsigned short Bsm[TM * BK];

    int row0 = blockIdx.y * TM;
    int tot = start[E_];
    if (row0 >= tot) return;
    int e = 0;
    while (e < E_ - 1 && row0 >= start[e + 1]) ++e;

    int n0 = blockIdx.x * TM;
    const unsigned short* Ag = xg + (size_t)row0 * D_;
    const unsigned short* Bg = w1t + (size_t)e * H_ * D_ + (size_t)n0 * D_;

    int tid = threadIdx.x;
    int wid = tid >> 6, lane = tid & 63;
    int wm = wid >> 1, wn = wid & 1;
    int quad = lane >> 4, r16 = lane & 15;
    int srow = (lane >> 3);                    // 0..7 within 8-row slab
    int scol = ((lane & 7) ^ srow) * 8;        // swizzled 16B group within row
    int rsw = r16 & 7;                         // reader-side XOR key

    floatx4 acc[4][4];
#pragma unroll
    for (int i = 0; i < 4; ++i)
#pragma unroll
        for (int j = 0; j < 4; ++j) acc[i][j] = (floatx4){0.f, 0.f, 0.f, 0.f};

    for (int kc = 0; kc < D_ / BK; ++kc) {
        int k0 = kc * BK;
#pragma unroll
        for (int q = 0; q < 4; ++q) {
            int rb = wid * 32 + q * 8;
            GLP16(Ag + (size_t)(rb + srow) * D_ + k0 + scol, Asm + rb * BK);
            GLP16(Bg + (size_t)(rb + srow) * D_ + k0 + scol, Bsm + rb * BK);
        }
        __syncthreads();
#pragma unroll
        for (int ks = 0; ks < 2; ++ks) {
            short8 af[4], bfr[4];
#pragma unroll
            for (int i = 0; i < 4; ++i)
                af[i] = *(const short8*)(Asm + (wm * 64 + i * 16 + r16) * BK + ((ks * 4 + quad) ^ rsw) * 8);
#pragma unroll
            for (int j = 0; j < 4; ++j)
                bfr[j] = *(const short8*)(Bsm + (wn * 64 + j * 16 + r16) * BK + ((ks * 4 + quad) ^ rsw) * 8);
#pragma unroll
            for (int i = 0; i < 4; ++i)
#pragma unroll
                for (int j = 0; j < 4; ++j)
                    acc[i][j] = __builtin_amdgcn_mfma_f32_16x16x32_bf16(af[i], bfr[j], acc[i][j], 0, 0, 0);
        }
        __syncthreads();
    }

    const float* b1e = b1 + (size_t)e * H_;
    float bj[4];
#pragma unroll
    for (int j = 0; j < 4; ++j) bj[j] = b1e[n0 + wn * 64 + j * 16 + r16];
#pragma unroll
    for (int i = 0; i < 4; ++i) {
#pragma unroll
        for (int r = 0; r < 4; ++r) {
            size_t rowg = (size_t)row0 + wm * 64 + i * 16 + quad * 4 + r;
            unsigned short* hp = h + rowg * H_ + n0 + wn * 64 + r16;
#pragma unroll
            for (int j = 0; j < 4; ++j) {
                float v = acc[i][j][r] + bj[j];
                v = 0.5f * v * (1.0f + erff(v * 0.70710678118654752f));  // exact gelu
                hp[j * 16] = f2bf(v);
            }
        }
    }
}

// ---------------- fc2: out[tok] += w * (h @ W2 + b2), split-K ----------------
// h: [CAP][H_] bf16. W2t: [E][D_][H_] bf16 (B^T). out: [T_][D_] fp32 (pre-zeroed).
// blockIdx.z = K-split slice; bias added by slice 0 only. atomicAdd composes slices.
__global__ __launch_bounds__(256) void fc2_kernel(
    const unsigned short* __restrict__ h, const unsigned short* __restrict__ w2t,
    const float* __restrict__ b2, const int* __restrict__ start,
    const int* __restrict__ tok, const float* __restrict__ wgt, float* __restrict__ out)
{
    __shared__ __align__(16) unsigned short Asm[TM * BK];
    __shared__ __align__(16) unsigned short Bsm[TM * BK];

    int row0 = blockIdx.y * TM;
    int tot = start[E_];
    if (row0 >= tot) return;
    int e = 0;
    while (e < E_ - 1 && row0 >= start[e + 1]) ++e;

    int n0 = blockIdx.x * TM;
    const unsigned short* Ag = h + (size_t)row0 * H_;
    const unsigned short* Bg = w2t + (size_t)e * D_ * H_ + (size_t)n0 * H_;

    int tid = threadIdx.x;
    int wid = tid >> 6, lane = tid & 63;
    int wm = wid >> 1, wn = wid & 1;
    int quad = lane >> 4, r16 = lane & 15;
    int srow = (lane >> 3);
    int scol = ((lane & 7) ^ srow) * 8;        // swizzled
    int rsw = r16 & 7;

    floatx4 acc[4][4];
#pragma unroll
    for (int i = 0; i < 4; ++i)
#pragma unroll
        for (int j = 0; j < 4; ++j) acc[i][j] = (floatx4){0.f, 0.f, 0.f, 0.f};

    const int KITERS = H_ / BK / SPLITK;       // 16
    int kbase = blockIdx.z * KITERS;
    for (int kc = kbase; kc < kbase + KITERS; ++kc) {
        int k0 = kc * BK;
#pragma unroll
        for (int q = 0; q < 4; ++q) {
            int rb = wid * 32 + q * 8;
            GLP16(Ag + (size_t)(rb + srow) * H_ + k0 + scol, Asm + rb * BK);
            GLP16(Bg + (size_t)(rb + srow) * H_ + k0 + scol, Bsm + rb * BK);
        }
        __syncthreads();
#pragma unroll
        for (int ks = 0; ks < 2; ++ks) {
            short8 af[4], bfr[4];
#pragma unroll
            for (int i = 0; i < 4; ++i)
                af[i] = *(const short8*)(Asm + (wm * 64 + i * 16 + r16) * BK + ((ks * 4 + quad) ^ rsw) * 8);
#pragma unroll
            for (int j = 0; j < 4; ++j)
                bfr[j] = *(const short8*)(Bsm + (wn * 64 + j * 16 + r16) * BK + ((ks * 4 + quad) ^ rsw) * 8);
#pragma unroll
            for (int i = 0; i < 4; ++i)
#pragma unroll
                for (int j = 0; j < 4; ++j)
                    acc[i][j] = __builtin_amdgcn_mfma_f32_16x16x32_bf16(af[i], bfr[j], acc[i][j], 0, 0, 0);
        }
        __syncthreads();
    }

    const float* b2e = b2 + (size_t)e * D_;
    float bj[4];
    bool addb = (blockIdx.z == 0);
#pragma unroll
    for (int j = 0; j < 4; ++j) bj[j] = addb ? b2e[n0 + wn * 64 + j * 16 + r16] : 0.f;
#pragma unroll
    for (int i = 0; i < 4; ++i) {
#pragma unroll
        for (int r = 0; r < 4; ++r) {
            int row = row0 + wm * 64 + i * 16 + quad * 4 + r;
            int t = tok[row];
            if (t < 0) continue;
            float w = wgt[row];
            float* op = out + (size_t)t * D_ + n0 + wn * 64 + r16;
#pragma unroll
            for (int j = 0; j < 4; ++j)
                atomicAdd(&op[j * 16], w * (acc[i][j][r] + bj[j]));
        }
    }
}

// ---------------- Launch ----------------
extern "C" void kernel_launch(void* const* d_in, const int* in_sizes, int n_in,
                              void* d_out, int out_size, void* d_ws, size_t ws_size,
                              hipStream_t stream)
{
    const float* x  = (const float*)d_in[0];
    const float* Wr = (const float*)d_in[1];
    const float* W1 = (const float*)d_in[2];
    const float* b1 = (const float*)d_in[3];
    const float* W2 = (const float*)d_in[4];
    const float* b2 = (const float*)d_in[5];
    float* out = (float*)d_out;

    // ws layout (needs ~300 MB)
    char* ws = (char*)d_ws;
    int*   cnt      = (int*)ws;                       // 8 ints
    int*   start    = (int*)(ws + 64);                // 9 ints
    int*   tok_list = (int*)(ws + 256);               // 8*8192 = 256 KiB
    float* w_list   = (float*)(ws + 256 + 262144);    // 256 KiB
    int*   tok      = (int*)(ws + 256 + 2 * 262144);  // CAP ints
    float* wgt      = (float*)(ws + 256 + 2 * 262144 + 69632);
    char* p = ws + (1u << 20);
    unsigned short* xg  = (unsigned short*)p; p += (size_t)CAP * D_ * 2;      // 35.7 MB
    unsigned short* h   = (unsigned short*)p; p += (size_t)CAP * H_ * 2;      // 142.6 MB
    unsigned short* w1t = (unsigned short*)p; p += (size_t)E_ * D_ * H_ * 2;  // 67 MB
    unsigned short* w2t = (unsigned short*)p;                                 // 67 MB
    (void)ws_size; (void)in_sizes; (void)n_in; (void)out_size;

    hipMemsetAsync(ws, 0, 256, stream);                                // zero cnt/start
    hipMemsetAsync(out, 0, (size_t)T_ * D_ * sizeof(float), stream);   // out accumulates via atomics

    transpose_cvt<<<dim3(H_ / 32, D_ / 32, E_), 256, 0, stream>>>(W1, w1t, D_, H_);
    transpose_cvt<<<dim3(D_ / 32, H_ / 32, E_), 256, 0, stream>>>(W2, w2t, H_, D_);
    router_kernel<<<T_, 64, 0, stream>>>(x, Wr, cnt, tok_list, w_list);
    offsets_kernel<<<1, 64, 0, stream>>>(cnt, start);
    gather_kernel<<<CAP, 256, 0, stream>>>(x, cnt, start, tok_list, w_list, xg, tok, wgt);
    fc1_kernel<<<dim3(H_ / TM, NBY), 256, 0, stream>>>(xg, w1t, b1, start, h);
    fc2_kernel<<<dim3(D_ / TM, NBY, SPLITK), 256, 0, stream>>>(h, w2t, b2, start, tok, wgt, out);
}

// Round 3
// 971.399 us; speedup vs baseline: 1.2468x; 1.2468x over previous
//
#include <hip/hip_runtime.h>
#include <hip/hip_bf16.h>

// Problem constants (from reference)
#define E_   8
#define D_   1024
#define H_   4096
#define T_   8192      // B*S tokens
#define TM   128       // GEMM M/N tile
#define BK   64        // GEMM K chunk (bf16)
#define CAP  17408     // 136*128 >= 16384 + 8*127 padded capacity
#define NBY  136       // CAP/TM
#define CK   2         // fc2 K-split (K=4096 -> 2 x 2048), separate y slices

typedef __attribute__((ext_vector_type(8))) short short8;   // 8 bf16 = 4 VGPRs (MFMA A/B frag)
typedef __attribute__((ext_vector_type(4))) float floatx4;  // MFMA C/D frag

__device__ __forceinline__ unsigned short f2bf(float f) {
    unsigned u = __float_as_uint(f);
    u += 0x7fffu + ((u >> 16) & 1u);   // RNE truncate to bf16
    return (unsigned short)(u >> 16);
}
__device__ __forceinline__ float bf2f(unsigned short u) {
    return __uint_as_float((unsigned)u << 16);
}

// direct global->LDS async copy, 16B/lane; lds base must be wave-uniform
#define GLP16(g, l)                                                             \
    __builtin_amdgcn_global_load_lds((const __attribute__((address_space(1))) void*)(g), \
                                     (__attribute__((address_space(3))) void*)(l), 16, 0, 0)

// ---------------- Router: 1 wave per token ----------------
__global__ __launch_bounds__(64) void router_kernel(
    const float* __restrict__ x, const float* __restrict__ Wr,
    int* __restrict__ cnt, int* __restrict__ tok_list,
    int2* __restrict__ inv_ei, float2* __restrict__ inv_w)
{
    int t = blockIdx.x;
    int lane = threadIdx.x;
    const float* xr = x + (size_t)t * D_;
    float acc[E_];
#pragma unroll
    for (int e = 0; e < E_; ++e) acc[e] = 0.f;
    for (int it = 0; it < D_ / 64; ++it) {
        float xv = xr[lane + it * 64];
#pragma unroll
        for (int e = 0; e < E_; ++e) acc[e] += xv * Wr[e * D_ + lane + it * 64];
    }
#pragma unroll
    for (int e = 0; e < E_; ++e) {
#pragma unroll
        for (int off = 32; off; off >>= 1) acc[e] += __shfl_xor(acc[e], off);
    }
    if (lane == 0) {
        float m = acc[0];
#pragma unroll
        for (int e = 1; e < E_; ++e) m = fmaxf(m, acc[e]);
        float p[E_]; float s = 0.f;
#pragma unroll
        for (int e = 0; e < E_; ++e) { p[e] = expf(acc[e] - m); s += p[e]; }
        float inv = 1.f / s;
        int i1 = 0; float v1 = p[0];
#pragma unroll
        for (int e = 1; e < E_; ++e) if (p[e] > v1) { v1 = p[e]; i1 = e; }
        int i2 = -1; float v2 = -1.f;
#pragma unroll
        for (int e = 0; e < E_; ++e) { if (e == i1) continue; if (p[e] > v2) { v2 = p[e]; i2 = e; } }
        v1 *= inv; v2 *= inv;
        int pos1 = atomicAdd(&cnt[i1], 1);
        tok_list[i1 * T_ + pos1] = t;
        int pos2 = atomicAdd(&cnt[i2], 1);
        tok_list[i2 * T_ + pos2] = t;
        inv_ei[t] = make_int2(i1 | (pos1 << 3), i2 | (pos2 << 3));
        inv_w[t] = make_float2(v1, v2);
    }
}

// ---------------- Prefix: 128-aligned expert regions ----------------
__global__ void offsets_kernel(const int* __restrict__ cnt, int* __restrict__ start)
{
    if (threadIdx.x == 0) {
        int s = 0;
        for (int e = 0; e < E_; ++e) {
            start[e] = s;
            s += (cnt[e] + TM - 1) / TM * TM;
        }
        start[E_] = s;
    }
}

// ---------------- Gather x rows -> bf16 ----------------
__global__ __launch_bounds__(256) void gather_kernel(
    const float* __restrict__ x, const int* __restrict__ cnt, const int* __restrict__ start,
    const int* __restrict__ tok_list, unsigned short* __restrict__ xg)
{
    int row = blockIdx.x;
    int tid = threadIdx.x;
    int tot = start[E_];
    if (row >= tot) return;
    int e = 0;
    while (e < E_ - 1 && row >= start[e + 1]) ++e;
    int idx = row - start[e];
    unsigned short* dst = xg + (size_t)row * D_;
    if (idx < cnt[e]) {
        int t = tok_list[e * T_ + idx];
        const float4* src = (const float4*)(x + (size_t)t * D_);
        float4 v = src[tid];
        ushort4 o; o.x = f2bf(v.x); o.y = f2bf(v.y); o.z = f2bf(v.z); o.w = f2bf(v.w);
        ((ushort4*)dst)[tid] = o;
    } else {
        ((ushort4*)dst)[tid] = make_ushort4(0, 0, 0, 0);  // zero pad rows
    }
}

// ---------------- Transpose + fp32->bf16: in[E][R][C] -> out[E][C][R] ----------------
__global__ __launch_bounds__(256) void transpose_cvt(
    const float* __restrict__ in, unsigned short* __restrict__ out, int R, int C)
{
    __shared__ float tile[32][33];
    int e = blockIdx.z;
    int c0 = blockIdx.x * 32, r0 = blockIdx.y * 32;
    const float* src = in + (size_t)e * R * C;
    unsigned short* dst = out + (size_t)e * R * C;
    int tx = threadIdx.x & 31, ty = threadIdx.x >> 5;
#pragma unroll
    for (int i = 0; i < 32; i += 8)
        tile[ty + i][tx] = src[(size_t)(r0 + ty + i) * C + c0 + tx];
    __syncthreads();
#pragma unroll
    for (int i = 0; i < 32; i += 8)
        dst[(size_t)(c0 + ty + i) * R + r0 + tx] = f2bf(tile[tx][ty + i]);
}

// ---------------- fc1: h = gelu(Xg @ W1 + b1), bf16 out ----------------
// Xg: [CAP][D_] bf16 row-major. W1t: [E][H_][D_] bf16 (B^T). h: [CAP][H_] bf16.
// LDS XOR-swizzled (16B group cg stored at cg ^ (row&7)) -> 0 bank conflicts.
__global__ __launch_bounds__(256) void fc1_kernel(
    const unsigned short* __restrict__ xg, const unsigned short* __restrict__ w1t,
    const float* __restrict__ b1, const int* __restrict__ start, unsigned short* __restrict__ h)
{
    __shared__ __align__(16) unsigned short Asm[TM * BK];
    __shared__ __align__(16) unsigned short Bsm[TM * BK];

    int row0 = blockIdx.y * TM;
    int tot = start[E_];
    if (row0 >= tot) return;
    int e = 0;
    while (e < E_ - 1 && row0 >= start[e + 1]) ++e;

    int n0 = blockIdx.x * TM;
    const unsigned short* Ag = xg + (size_t)row0 * D_;
    const unsigned short* Bg = w1t + (size_t)e * H_ * D_ + (size_t)n0 * D_;

    int tid = threadIdx.x;
    int wid = tid >> 6, lane = tid & 63;
    int wm = wid >> 1, wn = wid & 1;
    int quad = lane >> 4, r16 = lane & 15;
    int srow = (lane >> 3);                    // 0..7 within 8-row slab
    int scol = ((lane & 7) ^ srow) * 8;        // swizzled 16B group within row
    int rsw = r16 & 7;                         // reader-side XOR key

    floatx4 acc[4][4];
#pragma unroll
    for (int i = 0; i < 4; ++i)
#pragma unroll
        for (int j = 0; j < 4; ++j) acc[i][j] = (floatx4){0.f, 0.f, 0.f, 0.f};

    for (int kc = 0; kc < D_ / BK; ++kc) {
        int k0 = kc * BK;
#pragma unroll
        for (int q = 0; q < 4; ++q) {
            int rb = wid * 32 + q * 8;
            GLP16(Ag + (size_t)(rb + srow) * D_ + k0 + scol, Asm + rb * BK);
            GLP16(Bg + (size_t)(rb + srow) * D_ + k0 + scol, Bsm + rb * BK);
        }
        __syncthreads();
#pragma unroll
        for (int ks = 0; ks < 2; ++ks) {
            short8 af[4], bfr[4];
#pragma unroll
            for (int i = 0; i < 4; ++i)
                af[i] = *(const short8*)(Asm + (wm * 64 + i * 16 + r16) * BK + ((ks * 4 + quad) ^ rsw) * 8);
#pragma unroll
            for (int j = 0; j < 4; ++j)
                bfr[j] = *(const short8*)(Bsm + (wn * 64 + j * 16 + r16) * BK + ((ks * 4 + quad) ^ rsw) * 8);
#pragma unroll
            for (int i = 0; i < 4; ++i)
#pragma unroll
                for (int j = 0; j < 4; ++j)
                    acc[i][j] = __builtin_amdgcn_mfma_f32_16x16x32_bf16(af[i], bfr[j], acc[i][j], 0, 0, 0);
        }
        __syncthreads();
    }

    const float* b1e = b1 + (size_t)e * H_;
    float bj[4];
#pragma unroll
    for (int j = 0; j < 4; ++j) bj[j] = b1e[n0 + wn * 64 + j * 16 + r16];
#pragma unroll
    for (int i = 0; i < 4; ++i) {
#pragma unroll
        for (int r = 0; r < 4; ++r) {
            size_t rowg = (size_t)row0 + wm * 64 + i * 16 + quad * 4 + r;
            unsigned short* hp = h + rowg * H_ + n0 + wn * 64 + r16;
#pragma unroll
            for (int j = 0; j < 4; ++j) {
                float v = acc[i][j][r] + bj[j];
                // tanh-form gelu: v * sigmoid(1.5957691*(v + 0.044715 v^3)); max err ~3e-4
                float u = 1.5957691f * v * fmaf(0.044715f, v * v, 1.f);
                float g = v * __builtin_amdgcn_rcpf(1.f + __expf(-u));
                hp[j * 16] = f2bf(g);
            }
        }
    }
}

// ---------------- fc2: y_s = h @ W2 (K-slice s), bf16 out, NO atomics ----------------
// h: [CAP][H_] bf16. W2t: [E][D_][H_] bf16 (B^T). y: [CK][CAP][D_] bf16.
__global__ __launch_bounds__(256) void fc2_kernel(
    const unsigned short* __restrict__ h, const unsigned short* __restrict__ w2t,
    const int* __restrict__ start, unsigned short* __restrict__ y)
{
    __shared__ __align__(16) unsigned short Asm[TM * BK];
    __shared__ __align__(16) unsigned short Bsm[TM * BK];

    int row0 = blockIdx.y * TM;
    int tot = start[E_];
    if (row0 >= tot) return;
    int e = 0;
    while (e < E_ - 1 && row0 >= start[e + 1]) ++e;

    int n0 = blockIdx.x * TM;
    const unsigned short* Ag = h + (size_t)row0 * H_;
    const unsigned short* Bg = w2t + (size_t)e * D_ * H_ + (size_t)n0 * H_;

    int tid = threadIdx.x;
    int wid = tid >> 6, lane = tid & 63;
    int wm = wid >> 1, wn = wid & 1;
    int quad = lane >> 4, r16 = lane & 15;
    int srow = (lane >> 3);
    int scol = ((lane & 7) ^ srow) * 8;        // swizzled
    int rsw = r16 & 7;

    floatx4 acc[4][4];
#pragma unroll
    for (int i = 0; i < 4; ++i)
#pragma unroll
        for (int j = 0; j < 4; ++j) acc[i][j] = (floatx4){0.f, 0.f, 0.f, 0.f};

    const int KITERS = H_ / BK / CK;           // 32
    int kbase = blockIdx.z * KITERS;
    for (int kc = kbase; kc < kbase + KITERS; ++kc) {
        int k0 = kc * BK;
#pragma unroll
        for (int q = 0; q < 4; ++q) {
            int rb = wid * 32 + q * 8;
            GLP16(Ag + (size_t)(rb + srow) * H_ + k0 + scol, Asm + rb * BK);
            GLP16(Bg + (size_t)(rb + srow) * H_ + k0 + scol, Bsm + rb * BK);
        }
        __syncthreads();
#pragma unroll
        for (int ks = 0; ks < 2; ++ks) {
            short8 af[4], bfr[4];
#pragma unroll
            for (int i = 0; i < 4; ++i)
                af[i] = *(const short8*)(Asm + (wm * 64 + i * 16 + r16) * BK + ((ks * 4 + quad) ^ rsw) * 8);
#pragma unroll
            for (int j = 0; j < 4; ++j)
                bfr[j] = *(const short8*)(Bsm + (wn * 64 + j * 16 + r16) * BK + ((ks * 4 + quad) ^ rsw) * 8);
#pragma unroll
            for (int i = 0; i < 4; ++i)
#pragma unroll
                for (int j = 0; j < 4; ++j)
                    acc[i][j] = __builtin_amdgcn_mfma_f32_16x16x32_bf16(af[i], bfr[j], acc[i][j], 0, 0, 0);
        }
        __syncthreads();
    }

    unsigned short* ys = y + (size_t)blockIdx.z * CAP * D_;
#pragma unroll
    for (int i = 0; i < 4; ++i) {
#pragma unroll
        for (int r = 0; r < 4; ++r) {
            int row = row0 + wm * 64 + i * 16 + quad * 4 + r;
            unsigned short* op = ys + (size_t)row * D_ + n0 + wn * 64 + r16;
#pragma unroll
            for (int j = 0; j < 4; ++j)
                op[j * 16] = f2bf(acc[i][j][r]);
        }
    }
}

// ---------------- Combine: out[t] = sum_k w_k * (sum_s y_s[row_k] + b2[e_k]) ----------------
__global__ __launch_bounds__(256) void combine_kernel(
    const unsigned short* __restrict__ y, const int* __restrict__ start,
    const int2* __restrict__ inv_ei, const float2* __restrict__ inv_w,
    const float* __restrict__ b2, float* __restrict__ out)
{
    int t = blockIdx.x;
    int tid = threadIdx.x;       // 256 threads x 4 floats = D_
    int2 ei = inv_ei[t];
    float2 w = inv_w[t];
    int e1 = ei.x & 7, x1 = ei.x >> 3;
    int e2 = ei.y & 7, x2 = ei.y >> 3;
    size_t r1 = (size_t)start[e1] + x1;
    size_t r2 = (size_t)start[e2] + x2;
    const size_t SL = (size_t)CAP * D_;
    ushort4 a0 = ((const ushort4*)(y + r1 * D_))[tid];
    ushort4 a1 = ((const ushort4*)(y + SL + r1 * D_))[tid];
    ushort4 c0 = ((const ushort4*)(y + r2 * D_))[tid];
    ushort4 c1 = ((const ushort4*)(y + SL + r2 * D_))[tid];
    float4 bA = ((const float4*)(b2 + (size_t)e1 * D_))[tid];
    float4 bB = ((const float4*)(b2 + (size_t)e2 * D_))[tid];
    float4 o;
    o.x = w.x * (bf2f(a0.x) + bf2f(a1.x) + bA.x) + w.y * (bf2f(c0.x) + bf2f(c1.x) + bB.x);
    o.y = w.x * (bf2f(a0.y) + bf2f(a1.y) + bA.y) + w.y * (bf2f(c0.y) + bf2f(c1.y) + bB.y);
    o.z = w.x * (bf2f(a0.z) + bf2f(a1.z) + bA.z) + w.y * (bf2f(c0.z) + bf2f(c1.z) + bB.z);
    o.w = w.x * (bf2f(a0.w) + bf2f(a1.w) + bA.w) + w.y * (bf2f(c0.w) + bf2f(c1.w) + bB.w);
    ((float4*)(out + (size_t)t * D_))[tid] = o;
}

// ---------------- Launch ----------------
extern "C" void kernel_launch(void* const* d_in, const int* in_sizes, int n_in,
                              void* d_out, int out_size, void* d_ws, size_t ws_size,
                              hipStream_t stream)
{
    const float* x  = (const float*)d_in[0];
    const float* Wr = (const float*)d_in[1];
    const float* W1 = (const float*)d_in[2];
    const float* b1 = (const float*)d_in[3];
    const float* W2 = (const float*)d_in[4];
    const float* b2 = (const float*)d_in[5];
    float* out = (float*)d_out;

    // ws layout (~313 MB)
    char* ws = (char*)d_ws;
    int*    cnt      = (int*)ws;                    // 32 B
    int*    start    = (int*)(ws + 64);             // 36 B
    int*    tok_list = (int*)(ws + 256);            // 256 KiB
    int2*   inv_ei   = (int2*)(ws + 393216);        // 64 KiB
    float2* inv_w    = (float2*)(ws + 458752);      // 64 KiB
    char* p0 = ws + (1u << 20);
    unsigned short* xg  = (unsigned short*)p0;                                  // 35.65 MB
    unsigned short* w1t = (unsigned short*)(p0 + 35651584ull);                  // 67.1 MB
    unsigned short* h   = (unsigned short*)(p0 + 35651584ull + 67108864ull);    // 142.6 MB
    unsigned short* w2t = (unsigned short*)(p0 + 35651584ull + 67108864ull + 142606336ull); // 67.1 MB
    // y aliases xg+w1t (both dead after fc1): 2 slices x 35.65 MB = 71.3 MB <= 102.8 MB
    unsigned short* y   = (unsigned short*)p0;
    (void)ws_size; (void)in_sizes; (void)n_in; (void)out_size;

    hipMemsetAsync(ws, 0, 64, stream);   // zero cnt

    transpose_cvt<<<dim3(H_ / 32, D_ / 32, E_), 256, 0, stream>>>(W1, w1t, D_, H_);
    transpose_cvt<<<dim3(D_ / 32, H_ / 32, E_), 256, 0, stream>>>(W2, w2t, H_, D_);
    router_kernel<<<T_, 64, 0, stream>>>(x, Wr, cnt, tok_list, inv_ei, inv_w);
    offsets_kernel<<<1, 64, 0, stream>>>(cnt, start);
    gather_kernel<<<CAP, 256, 0, stream>>>(x, cnt, start, tok_list, xg);
    fc1_kernel<<<dim3(H_ / TM, NBY), 256, 0, stream>>>(xg, w1t, b1, start, h);
    fc2_kernel<<<dim3(D_ / TM, NBY, CK), 256, 0, stream>>>(h, w2t, start, y);
    combine_kernel<<<T_, 256, 0, stream>>>(y, start, inv_ei, inv_w, b2, out);
}

// Round 4
// 930.669 us; speedup vs baseline: 1.3013x; 1.0438x over previous
//
#include <hip/hip_runtime.h>
#include <hip/hip_bf16.h>

// Problem constants (from reference)
#define E_   8
#define D_   1024
#define H_   4096
#define T_   8192      // B*S tokens
#define TMM  128       // GEMM M tile (tokens)
#define TNN  256       // GEMM N tile
#define BK   64        // GEMM K chunk (bf16)
#define CAP  17408     // 136*128 >= 16384 + 8*127 padded capacity
#define NBY  136       // CAP/TMM
#define CK   2         // fc2 K-split (K=4096 -> 2 x 2048), separate y slices

typedef __attribute__((ext_vector_type(8))) short short8;     // 8 bf16 (MFMA A/B frag, 4 VGPR)
typedef __attribute__((ext_vector_type(16))) float floatx16;  // 32x32 MFMA C/D frag

__device__ __forceinline__ unsigned short f2bf(float f) {
    unsigned u = __float_as_uint(f);
    u += 0x7fffu + ((u >> 16) & 1u);   // RNE truncate to bf16
    return (unsigned short)(u >> 16);
}
__device__ __forceinline__ float bf2f(unsigned short u) {
    return __uint_as_float((unsigned)u << 16);
}

// direct global->LDS async copy, 16B/lane; lds base must be wave-uniform
#define GLP16(g, l)                                                             \
    __builtin_amdgcn_global_load_lds((const __attribute__((address_space(1))) void*)(g), \
                                     (__attribute__((address_space(3))) void*)(l), 16, 0, 0)

// ---------------- Router: 1 wave per token ----------------
__global__ __launch_bounds__(64) void router_kernel(
    const float* __restrict__ x, const float* __restrict__ Wr,
    int* __restrict__ cnt, int* __restrict__ tok_list,
    int2* __restrict__ inv_ei, float2* __restrict__ inv_w)
{
    int t = blockIdx.x;
    int lane = threadIdx.x;
    const float* xr = x + (size_t)t * D_;
    float acc[E_];
#pragma unroll
    for (int e = 0; e < E_; ++e) acc[e] = 0.f;
    for (int it = 0; it < D_ / 64; ++it) {
        float xv = xr[lane + it * 64];
#pragma unroll
        for (int e = 0; e < E_; ++e) acc[e] += xv * Wr[e * D_ + lane + it * 64];
    }
#pragma unroll
    for (int e = 0; e < E_; ++e) {
#pragma unroll
        for (int off = 32; off; off >>= 1) acc[e] += __shfl_xor(acc[e], off);
    }
    if (lane == 0) {
        float m = acc[0];
#pragma unroll
        for (int e = 1; e < E_; ++e) m = fmaxf(m, acc[e]);
        float p[E_]; float s = 0.f;
#pragma unroll
        for (int e = 0; e < E_; ++e) { p[e] = expf(acc[e] - m); s += p[e]; }
        float inv = 1.f / s;
        int i1 = 0; float v1 = p[0];
#pragma unroll
        for (int e = 1; e < E_; ++e) if (p[e] > v1) { v1 = p[e]; i1 = e; }
        int i2 = -1; float v2 = -1.f;
#pragma unroll
        for (int e = 0; e < E_; ++e) { if (e == i1) continue; if (p[e] > v2) { v2 = p[e]; i2 = e; } }
        v1 *= inv; v2 *= inv;
        int pos1 = atomicAdd(&cnt[i1], 1);
        tok_list[i1 * T_ + pos1] = t;
        int pos2 = atomicAdd(&cnt[i2], 1);
        tok_list[i2 * T_ + pos2] = t;
        inv_ei[t] = make_int2(i1 | (pos1 << 3), i2 | (pos2 << 3));
        inv_w[t] = make_float2(v1, v2);
    }
}

// ---------------- Prefix: 128-aligned expert regions ----------------
__global__ void offsets_kernel(const int* __restrict__ cnt, int* __restrict__ start)
{
    if (threadIdx.x == 0) {
        int s = 0;
        for (int e = 0; e < E_; ++e) {
            start[e] = s;
            s += (cnt[e] + TMM - 1) / TMM * TMM;
        }
        start[E_] = s;
    }
}

// ---------------- Gather x rows -> bf16 ----------------
__global__ __launch_bounds__(256) void gather_kernel(
    const float* __restrict__ x, const int* __restrict__ cnt, const int* __restrict__ start,
    const int* __restrict__ tok_list, unsigned short* __restrict__ xg)
{
    int row = blockIdx.x;
    int tid = threadIdx.x;
    int tot = start[E_];
    if (row >= tot) return;
    int e = 0;
    while (e < E_ - 1 && row >= start[e + 1]) ++e;
    int idx = row - start[e];
    unsigned short* dst = xg + (size_t)row * D_;
    if (idx < cnt[e]) {
        int t = tok_list[e * T_ + idx];
        const float4* src = (const float4*)(x + (size_t)t * D_);
        float4 v = src[tid];
        ushort4 o; o.x = f2bf(v.x); o.y = f2bf(v.y); o.z = f2bf(v.z); o.w = f2bf(v.w);
        ((ushort4*)dst)[tid] = o;
    } else {
        ((ushort4*)dst)[tid] = make_ushort4(0, 0, 0, 0);  // zero pad rows
    }
}

// ---------------- Fused transpose+cvt for W1 and W2 ----------------
// z<8: W1[e]: [D_][H_] -> w1t[e]: [H_][D_].  z>=8: W2[e-8]: [H_][D_] -> w2t: [D_][H_].
// 64x64 fp32 tile, float4 loads, ushort4 stores.
__global__ __launch_bounds__(256) void transpose_cvt(
    const float* __restrict__ W1, const float* __restrict__ W2,
    unsigned short* __restrict__ w1t, unsigned short* __restrict__ w2t)
{
    __shared__ float tile[64][65];
    int z = blockIdx.z;
    const float* src; unsigned short* dst; int R, C, r0, c0;
    if (z < 8) {
        src = W1 + (size_t)z * D_ * H_;       dst = w1t + (size_t)z * D_ * H_;
        R = D_; C = H_; r0 = blockIdx.y * 64; c0 = blockIdx.x * 64;
    } else {
        src = W2 + (size_t)(z - 8) * H_ * D_; dst = w2t + (size_t)(z - 8) * H_ * D_;
        R = H_; C = D_; r0 = blockIdx.x * 64; c0 = blockIdx.y * 64;
    }
    int t = threadIdx.x;
    int r = t >> 4, c4 = (t & 15) * 4;
#pragma unroll
    for (int p = 0; p < 4; ++p) {
        int row = p * 16 + r;
        float4 v = *(const float4*)(src + (size_t)(r0 + row) * C + c0 + c4);
        tile[row][c4 + 0] = v.x; tile[row][c4 + 1] = v.y;
        tile[row][c4 + 2] = v.z; tile[row][c4 + 3] = v.w;
    }
    __syncthreads();
#pragma unroll
    for (int p = 0; p < 4; ++p) {
        int orow = p * 16 + r;
        ushort4 o;
        o.x = f2bf(tile[c4 + 0][orow]); o.y = f2bf(tile[c4 + 1][orow]);
        o.z = f2bf(tile[c4 + 2][orow]); o.w = f2bf(tile[c4 + 3][orow]);
        *(ushort4*)(dst + (size_t)(c0 + orow) * R + r0 + c4) = o;
    }
}

// ---------------- fc1: h = gelu(Xg @ W1 + b1), bf16 out ----------------
// 128x256 tile, 512 threads (8 waves of 64x64), mfma_f32_32x32x16_bf16.
// LDS XOR-swizzled (16B group g stored at g ^ (row&7)) -> conflict-free.
__global__ __launch_bounds__(512) void fc1_kernel(
    const unsigned short* __restrict__ xg, const unsigned short* __restrict__ w1t,
    const float* __restrict__ b1, const int* __restrict__ start, unsigned short* __restrict__ h)
{
    __shared__ __align__(16) unsigned short Asm[TMM * BK];   // 16 KB
    __shared__ __align__(16) unsigned short Bsm[TNN * BK];   // 32 KB

    int row0 = blockIdx.y * TMM;
    int tot = start[E_];
    if (row0 >= tot) return;
    int e = 0;
    while (e < E_ - 1 && row0 >= start[e + 1]) ++e;

    int n0 = blockIdx.x * TNN;
    const unsigned short* Ag = xg + (size_t)row0 * D_;
    const unsigned short* Bg = w1t + (size_t)e * H_ * D_ + (size_t)n0 * D_;

    int tid = threadIdx.x;
    int wid = tid >> 6, lane = tid & 63;
    int wm = wid & 1, wn = wid >> 1;          // wave: rows wm*64, cols wn*64
    int m31 = lane & 31, khalf = lane >> 5;
    int srow = lane >> 3;                      // 0..7
    int scol = ((lane & 7) ^ srow) * 8;        // swizzled 16B group

    floatx16 acc[2][2];
#pragma unroll
    for (int i = 0; i < 2; ++i)
#pragma unroll
        for (int j = 0; j < 2; ++j)
#pragma unroll
            for (int r = 0; r < 16; ++r) acc[i][j][r] = 0.f;

    for (int kc = 0; kc < D_ / BK; ++kc) {
        int k0 = kc * BK;
#pragma unroll
        for (int q = 0; q < 2; ++q) {
            int rb = wid * 16 + q * 8;
            GLP16(Ag + (size_t)(rb + srow) * D_ + k0 + scol, Asm + rb * BK);
        }
#pragma unroll
        for (int q = 0; q < 4; ++q) {
            int rb = wid * 32 + q * 8;
            GLP16(Bg + (size_t)(rb + srow) * D_ + k0 + scol, Bsm + rb * BK);
        }
        __syncthreads();
#pragma unroll
        for (int ks = 0; ks < 4; ++ks) {
            int g = ((ks * 2 + khalf) ^ (lane & 7)) * 8;
            short8 af[2], bfr[2];
#pragma unroll
            for (int i = 0; i < 2; ++i)
                af[i] = *(const short8*)(Asm + (wm * 64 + i * 32 + m31) * BK + g);
#pragma unroll
            for (int j = 0; j < 2; ++j)
                bfr[j] = *(const short8*)(Bsm + (wn * 64 + j * 32 + m31) * BK + g);
#pragma unroll
            for (int i = 0; i < 2; ++i)
#pragma unroll
                for (int j = 0; j < 2; ++j)
                    acc[i][j] = __builtin_amdgcn_mfma_f32_32x32x16_bf16(af[i], bfr[j], acc[i][j], 0, 0, 0);
        }
        __syncthreads();
    }

    const float* b1e = b1 + (size_t)e * H_;
    int colb = n0 + wn * 64 + m31;
    float bb[2] = { b1e[colb], b1e[colb + 32] };
#pragma unroll
    for (int i = 0; i < 2; ++i) {
        int rb = row0 + wm * 64 + i * 32 + 4 * khalf;
#pragma unroll
        for (int j = 0; j < 2; ++j) {
#pragma unroll
            for (int reg = 0; reg < 16; ++reg) {
                int row = rb + (reg & 3) + 8 * (reg >> 2);
                float v = acc[i][j][reg] + bb[j];
                // tanh-form gelu: v * sigmoid(1.5957691*(v + 0.044715 v^3)); max err ~3e-4
                float u = 1.5957691f * v * fmaf(0.044715f, v * v, 1.f);
                float gl = v * __builtin_amdgcn_rcpf(1.f + __expf(-u));
                h[(size_t)row * H_ + colb + j * 32] = f2bf(gl);
            }
        }
    }
}

// ---------------- fc2: y_s = h @ W2 (K-slice s), bf16 out, NO atomics ----------------
__global__ __launch_bounds__(512) void fc2_kernel(
    const unsigned short* __restrict__ h, const unsigned short* __restrict__ w2t,
    const int* __restrict__ start, unsigned short* __restrict__ y)
{
    __shared__ __align__(16) unsigned short Asm[TMM * BK];
    __shared__ __align__(16) unsigned short Bsm[TNN * BK];

    int row0 = blockIdx.y * TMM;
    int tot = start[E_];
    if (row0 >= tot) return;
    int e = 0;
    while (e < E_ - 1 && row0 >= start[e + 1]) ++e;

    int n0 = blockIdx.x * TNN;
    const unsigned short* Ag = h + (size_t)row0 * H_;
    const unsigned short* Bg = w2t + (size_t)e * D_ * H_ + (size_t)n0 * H_;

    int tid = threadIdx.x;
    int wid = tid >> 6, lane = tid & 63;
    int wm = wid & 1, wn = wid >> 1;
    int m31 = lane & 31, khalf = lane >> 5;
    int srow = lane >> 3;
    int scol = ((lane & 7) ^ srow) * 8;

    floatx16 acc[2][2];
#pragma unroll
    for (int i = 0; i < 2; ++i)
#pragma unroll
        for (int j = 0; j < 2; ++j)
#pragma unroll
            for (int r = 0; r < 16; ++r) acc[i][j][r] = 0.f;

    const int KITERS = H_ / BK / CK;           // 32
    int kbase = blockIdx.z * KITERS;
    for (int kc = kbase; kc < kbase + KITERS; ++kc) {
        int k0 = kc * BK;
#pragma unroll
        for (int q = 0; q < 2; ++q) {
            int rb = wid * 16 + q * 8;
            GLP16(Ag + (size_t)(rb + srow) * H_ + k0 + scol, Asm + rb * BK);
        }
#pragma unroll
        for (int q = 0; q < 4; ++q) {
            int rb = wid * 32 + q * 8;
            GLP16(Bg + (size_t)(rb + srow) * H_ + k0 + scol, Bsm + rb * BK);
        }
        __syncthreads();
#pragma unroll
        for (int ks = 0; ks < 4; ++ks) {
            int g = ((ks * 2 + khalf) ^ (lane & 7)) * 8;
            short8 af[2], bfr[2];
#pragma unroll
            for (int i = 0; i < 2; ++i)
                af[i] = *(const short8*)(Asm + (wm * 64 + i * 32 + m31) * BK + g);
#pragma unroll
            for (int j = 0; j < 2; ++j)
                bfr[j] = *(const short8*)(Bsm + (wn * 64 + j * 32 + m31) * BK + g);
#pragma unroll
            for (int i = 0; i < 2; ++i)
#pragma unroll
                for (int j = 0; j < 2; ++j)
                    acc[i][j] = __builtin_amdgcn_mfma_f32_32x32x16_bf16(af[i], bfr[j], acc[i][j], 0, 0, 0);
        }
        __syncthreads();
    }

    unsigned short* ys = y + (size_t)blockIdx.z * CAP * D_;
    int colb = n0 + wn * 64 + m31;
#pragma unroll
    for (int i = 0; i < 2; ++i) {
        int rb = row0 + wm * 64 + i * 32 + 4 * khalf;
#pragma unroll
        for (int j = 0; j < 2; ++j) {
#pragma unroll
            for (int reg = 0; reg < 16; ++reg) {
                int row = rb + (reg & 3) + 8 * (reg >> 2);
                ys[(size_t)row * D_ + colb + j * 32] = f2bf(acc[i][j][reg]);
            }
        }
    }
}

// ---------------- Combine: out[t] = sum_k w_k * (sum_s y_s[row_k] + b2[e_k]) ----------------
__global__ __launch_bounds__(256) void combine_kernel(
    const unsigned short* __restrict__ y, const int* __restrict__ start,
    const int2* __restrict__ inv_ei, const float2* __restrict__ inv_w,
    const float* __restrict__ b2, float* __restrict__ out)
{
    int t = blockIdx.x;
    int tid = threadIdx.x;       // 256 threads x 4 floats = D_
    int2 ei = inv_ei[t];
    float2 w = inv_w[t];
    int e1 = ei.x & 7, x1 = ei.x >> 3;
    int e2 = ei.y & 7, x2 = ei.y >> 3;
    size_t r1 = (size_t)start[e1] + x1;
    size_t r2 = (size_t)start[e2] + x2;
    const size_t SL = (size_t)CAP * D_;
    ushort4 a0 = ((const ushort4*)(y + r1 * D_))[tid];
    ushort4 a1 = ((const ushort4*)(y + SL + r1 * D_))[tid];
    ushort4 c0 = ((const ushort4*)(y + r2 * D_))[tid];
    ushort4 c1 = ((const ushort4*)(y + SL + r2 * D_))[tid];
    float4 bA = ((const float4*)(b2 + (size_t)e1 * D_))[tid];
    float4 bB = ((const float4*)(b2 + (size_t)e2 * D_))[tid];
    float4 o;
    o.x = w.x * (bf2f(a0.x) + bf2f(a1.x) + bA.x) + w.y * (bf2f(c0.x) + bf2f(c1.x) + bB.x);
    o.y = w.x * (bf2f(a0.y) + bf2f(a1.y) + bA.y) + w.y * (bf2f(c0.y) + bf2f(c1.y) + bB.y);
    o.z = w.x * (bf2f(a0.z) + bf2f(a1.z) + bA.z) + w.y * (bf2f(c0.z) + bf2f(c1.z) + bB.z);
    o.w = w.x * (bf2f(a0.w) + bf2f(a1.w) + bA.w) + w.y * (bf2f(c0.w) + bf2f(c1.w) + bB.w);
    ((float4*)(out + (size_t)t * D_))[tid] = o;
}

// ---------------- Launch ----------------
extern "C" void kernel_launch(void* const* d_in, const int* in_sizes, int n_in,
                              void* d_out, int out_size, void* d_ws, size_t ws_size,
                              hipStream_t stream)
{
    const float* x  = (const float*)d_in[0];
    const float* Wr = (const float*)d_in[1];
    const float* W1 = (const float*)d_in[2];
    const float* b1 = (const float*)d_in[3];
    const float* W2 = (const float*)d_in[4];
    const float* b2 = (const float*)d_in[5];
    float* out = (float*)d_out;

    // ws layout (~313 MB)
    char* ws = (char*)d_ws;
    int*    cnt      = (int*)ws;                    // 32 B
    int*    start    = (int*)(ws + 64);             // 36 B
    int*    tok_list = (int*)(ws + 256);            // 256 KiB
    int2*   inv_ei   = (int2*)(ws + 393216);        // 64 KiB
    float2* inv_w    = (float2*)(ws + 458752);      // 64 KiB
    char* p0 = ws + (1u << 20);
    unsigned short* xg  = (unsigned short*)p0;                                  // 35.65 MB
    unsigned short* w1t = (unsigned short*)(p0 + 35651584ull);                  // 67.1 MB
    unsigned short* h   = (unsigned short*)(p0 + 35651584ull + 67108864ull);    // 142.6 MB
    unsigned short* w2t = (unsigned short*)(p0 + 35651584ull + 67108864ull + 142606336ull); // 67.1 MB
    // y aliases xg+w1t (both dead after fc1): 2 slices x 35.65 MB = 71.3 MB <= 102.8 MB
    unsigned short* y   = (unsigned short*)p0;
    (void)ws_size; (void)in_sizes; (void)n_in; (void)out_size;

    hipMemsetAsync(ws, 0, 64, stream);   // zero cnt

    transpose_cvt<<<dim3(64, 16, 16), 256, 0, stream>>>(W1, W2, w1t, w2t);
    router_kernel<<<T_, 64, 0, stream>>>(x, Wr, cnt, tok_list, inv_ei, inv_w);
    offsets_kernel<<<1, 64, 0, stream>>>(cnt, start);
    gather_kernel<<<CAP, 256, 0, stream>>>(x, cnt, start, tok_list, xg);
    fc1_kernel<<<dim3(H_ / TNN, NBY), 512, 0, stream>>>(xg, w1t, b1, start, h);
    fc2_kernel<<<dim3(D_ / TNN, NBY, CK), 512, 0, stream>>>(h, w2t, start, y);
    combine_kernel<<<T_, 256, 0, stream>>>(y, start, inv_ei, inv_w, b2, out);
}

// Round 5
// 913.656 us; speedup vs baseline: 1.3255x; 1.0186x over previous
//
#include <hip/hip_runtime.h>
#include <hip/hip_bf16.h>

// Problem constants (from reference)
#define E_   8
#define D_   1024
#define H_   4096
#define T_   8192      // B*S tokens
#define TMM  128       // GEMM M tile (tokens)
#define TNN  256       // GEMM N tile
#define BK   64        // GEMM K chunk (bf16)
#define CAP  17408     // 136*128 >= 16384 + 8*127 padded capacity
#define NBY  136       // CAP/TMM
#define CK   2         // fc2 K-split (K=4096 -> 2 x 2048), separate y slices

typedef __attribute__((ext_vector_type(8))) short short8;   // 8 bf16 (MFMA A/B frag, 4 VGPR)
typedef __attribute__((ext_vector_type(4))) float floatx4;  // 16x16 MFMA C/D frag

__device__ __forceinline__ unsigned short f2bf(float f) {
    unsigned u = __float_as_uint(f);
    u += 0x7fffu + ((u >> 16) & 1u);   // RNE truncate to bf16
    return (unsigned short)(u >> 16);
}
__device__ __forceinline__ float bf2f(unsigned short u) {
    return __uint_as_float((unsigned)u << 16);
}

// direct global->LDS async copy, 16B/lane; lds base must be wave-uniform
#define GLP16(g, l)                                                             \
    __builtin_amdgcn_global_load_lds((const __attribute__((address_space(1))) void*)(g), \
                                     (__attribute__((address_space(3))) void*)(l), 16, 0, 0)

// ---------------- Router: 4 waves/block, 1 token/wave, float4 loads ----------------
__global__ __launch_bounds__(256) void router_kernel(
    const float* __restrict__ x, const float* __restrict__ Wr,
    int* __restrict__ cnt, int* __restrict__ tok_list,
    int2* __restrict__ inv_ei, float2* __restrict__ inv_w)
{
    int t = blockIdx.x * 4 + (threadIdx.x >> 6);
    int lane = threadIdx.x & 63;
    const float4* xr = (const float4*)(x + (size_t)t * D_);
    float acc[E_];
#pragma unroll
    for (int e = 0; e < E_; ++e) acc[e] = 0.f;
#pragma unroll
    for (int it = 0; it < D_ / 256; ++it) {
        float4 xv = xr[lane + it * 64];
#pragma unroll
        for (int e = 0; e < E_; ++e) {
            float4 wv = ((const float4*)(Wr + e * D_))[lane + it * 64];
            acc[e] += xv.x * wv.x + xv.y * wv.y + xv.z * wv.z + xv.w * wv.w;
        }
    }
#pragma unroll
    for (int e = 0; e < E_; ++e) {
#pragma unroll
        for (int off = 32; off; off >>= 1) acc[e] += __shfl_xor(acc[e], off);
    }
    if (lane == 0) {
        float m = acc[0];
#pragma unroll
        for (int e = 1; e < E_; ++e) m = fmaxf(m, acc[e]);
        float p[E_]; float s = 0.f;
#pragma unroll
        for (int e = 0; e < E_; ++e) { p[e] = expf(acc[e] - m); s += p[e]; }
        float inv = 1.f / s;
        int i1 = 0; float v1 = p[0];
#pragma unroll
        for (int e = 1; e < E_; ++e) if (p[e] > v1) { v1 = p[e]; i1 = e; }
        int i2 = -1; float v2 = -1.f;
#pragma unroll
        for (int e = 0; e < E_; ++e) { if (e == i1) continue; if (p[e] > v2) { v2 = p[e]; i2 = e; } }
        v1 *= inv; v2 *= inv;
        int pos1 = atomicAdd(&cnt[i1], 1);
        tok_list[i1 * T_ + pos1] = t;
        int pos2 = atomicAdd(&cnt[i2], 1);
        tok_list[i2 * T_ + pos2] = t;
        inv_ei[t] = make_int2(i1 | (pos1 << 3), i2 | (pos2 << 3));
        inv_w[t] = make_float2(v1, v2);
    }
}

// ---------------- Prefix: 128-aligned expert regions ----------------
__global__ void offsets_kernel(const int* __restrict__ cnt, int* __restrict__ start)
{
    if (threadIdx.x == 0) {
        int s = 0;
        for (int e = 0; e < E_; ++e) {
            start[e] = s;
            s += (cnt[e] + TMM - 1) / TMM * TMM;
        }
        start[E_] = s;
    }
}

// ---------------- Gather x rows -> bf16 ----------------
__global__ __launch_bounds__(256) void gather_kernel(
    const float* __restrict__ x, const int* __restrict__ cnt, const int* __restrict__ start,
    const int* __restrict__ tok_list, unsigned short* __restrict__ xg)
{
    int row = blockIdx.x;
    int tid = threadIdx.x;
    int tot = start[E_];
    if (row >= tot) return;
    int e = 0;
    while (e < E_ - 1 && row >= start[e + 1]) ++e;
    int idx = row - start[e];
    unsigned short* dst = xg + (size_t)row * D_;
    if (idx < cnt[e]) {
        int t = tok_list[e * T_ + idx];
        const float4* src = (const float4*)(x + (size_t)t * D_);
        float4 v = src[tid];
        ushort4 o; o.x = f2bf(v.x); o.y = f2bf(v.y); o.z = f2bf(v.z); o.w = f2bf(v.w);
        ((ushort4*)dst)[tid] = o;
    } else {
        ((ushort4*)dst)[tid] = make_ushort4(0, 0, 0, 0);  // zero pad rows
    }
}

// ---------------- Fused transpose+cvt for W1 and W2 ----------------
// z<8: W1[e]: [D_][H_] -> w1t[e]: [H_][D_].  z>=8: W2[e-8]: [H_][D_] -> w2t: [D_][H_].
__global__ __launch_bounds__(256) void transpose_cvt(
    const float* __restrict__ W1, const float* __restrict__ W2,
    unsigned short* __restrict__ w1t, unsigned short* __restrict__ w2t)
{
    __shared__ float tile[64][65];
    int z = blockIdx.z;
    const float* src; unsigned short* dst; int R, C, r0, c0;
    if (z < 8) {
        src = W1 + (size_t)z * D_ * H_;       dst = w1t + (size_t)z * D_ * H_;
        R = D_; C = H_; r0 = blockIdx.y * 64; c0 = blockIdx.x * 64;
    } else {
        src = W2 + (size_t)(z - 8) * H_ * D_; dst = w2t + (size_t)(z - 8) * H_ * D_;
        R = H_; C = D_; r0 = blockIdx.x * 64; c0 = blockIdx.y * 64;
    }
    int t = threadIdx.x;
    int r = t >> 4, c4 = (t & 15) * 4;
#pragma unroll
    for (int p = 0; p < 4; ++p) {
        int row = p * 16 + r;
        float4 v = *(const float4*)(src + (size_t)(r0 + row) * C + c0 + c4);
        tile[row][c4 + 0] = v.x; tile[row][c4 + 1] = v.y;
        tile[row][c4 + 2] = v.z; tile[row][c4 + 3] = v.w;
    }
    __syncthreads();
#pragma unroll
    for (int p = 0; p < 4; ++p) {
        int orow = p * 16 + r;
        ushort4 o;
        o.x = f2bf(tile[c4 + 0][orow]); o.y = f2bf(tile[c4 + 1][orow]);
        o.z = f2bf(tile[c4 + 2][orow]); o.w = f2bf(tile[c4 + 3][orow]);
        *(ushort4*)(dst + (size_t)(c0 + orow) * R + r0 + c4) = o;
    }
}

// ---------------- fc1: h = gelu(Xg @ W1 + b1), bf16 out ----------------
// 128x256 tile, 512 threads (8 waves, 2m x 4n), each wave 4x4 frags of 16x16x32.
// Reader pattern = R3's verified zero-conflict XOR swizzle.
// grid: x = n-block (16), y = m-block -> consecutive blocks share the A slab (L2-hot).
__global__ __launch_bounds__(512) void fc1_kernel(
    const unsigned short* __restrict__ xg, const unsigned short* __restrict__ w1t,
    const float* __restrict__ b1, const int* __restrict__ start, unsigned short* __restrict__ h)
{
    __shared__ __align__(16) unsigned short Asm[TMM * BK];   // 16 KB
    __shared__ __align__(16) unsigned short Bsm[TNN * BK];   // 32 KB

    int row0 = blockIdx.y * TMM;
    int tot = start[E_];
    if (row0 >= tot) return;
    int e = 0;
    while (e < E_ - 1 && row0 >= start[e + 1]) ++e;

    int n0 = blockIdx.x * TNN;
    const unsigned short* Ag = xg + (size_t)row0 * D_;
    const unsigned short* Bg = w1t + (size_t)e * H_ * D_ + (size_t)n0 * D_;

    int tid = threadIdx.x;
    int wid = tid >> 6, lane = tid & 63;
    int wm = wid & 1, wn = wid >> 1;          // wave covers rows wm*64+, cols wn*64+
    int quad = lane >> 4, r16 = lane & 15;
    int srow = lane >> 3;                      // 0..7
    int scol = ((lane & 7) ^ srow) * 8;        // swizzled 16B group
    int rsw = r16 & 7;                         // reader XOR key

    floatx4 acc[4][4];
#pragma unroll
    for (int i = 0; i < 4; ++i)
#pragma unroll
        for (int j = 0; j < 4; ++j) acc[i][j] = (floatx4){0.f, 0.f, 0.f, 0.f};

    for (int kc = 0; kc < D_ / BK; ++kc) {
        int k0 = kc * BK;
#pragma unroll
        for (int q = 0; q < 2; ++q) {
            int rb = wid * 16 + q * 8;
            GLP16(Ag + (size_t)(rb + srow) * D_ + k0 + scol, Asm + rb * BK);
        }
#pragma unroll
        for (int q = 0; q < 4; ++q) {
            int rb = wid * 32 + q * 8;
            GLP16(Bg + (size_t)(rb + srow) * D_ + k0 + scol, Bsm + rb * BK);
        }
        __syncthreads();
#pragma unroll
        for (int ks = 0; ks < 2; ++ks) {
            short8 af[4], bfr[4];
#pragma unroll
            for (int i = 0; i < 4; ++i)
                af[i] = *(const short8*)(Asm + (wm * 64 + i * 16 + r16) * BK + ((ks * 4 + quad) ^ rsw) * 8);
#pragma unroll
            for (int j = 0; j < 4; ++j)
                bfr[j] = *(const short8*)(Bsm + (wn * 64 + j * 16 + r16) * BK + ((ks * 4 + quad) ^ rsw) * 8);
#pragma unroll
            for (int i = 0; i < 4; ++i)
#pragma unroll
                for (int j = 0; j < 4; ++j)
                    acc[i][j] = __builtin_amdgcn_mfma_f32_16x16x32_bf16(af[i], bfr[j], acc[i][j], 0, 0, 0);
        }
        __syncthreads();
    }

    const float* b1e = b1 + (size_t)e * H_;
    float bj[4];
#pragma unroll
    for (int j = 0; j < 4; ++j) bj[j] = b1e[n0 + wn * 64 + j * 16 + r16];
#pragma unroll
    for (int i = 0; i < 4; ++i) {
#pragma unroll
        for (int r = 0; r < 4; ++r) {
            size_t rowg = (size_t)row0 + wm * 64 + i * 16 + quad * 4 + r;
            unsigned short* hp = h + rowg * H_ + n0 + wn * 64 + r16;
#pragma unroll
            for (int j = 0; j < 4; ++j) {
                float v = acc[i][j][r] + bj[j];
                // tanh-form gelu: v * sigmoid(1.5957691*(v + 0.044715 v^3)); max err ~3e-4
                float u = 1.5957691f * v * fmaf(0.044715f, v * v, 1.f);
                float gl = v * __builtin_amdgcn_rcpf(1.f + __expf(-u));
                hp[j * 16] = f2bf(gl);
            }
        }
    }
}

// ---------------- fc2: y_s = h @ W2 (K-slice s), bf16 out, NO atomics ----------------
// grid: x = n-block(4) | ck(2) folded (8 total), y = m-block -> consecutive blocks
// share the 1 MB h slab (L2-hot).
__global__ __launch_bounds__(512) void fc2_kernel(
    const unsigned short* __restrict__ h, const unsigned short* __restrict__ w2t,
    const int* __restrict__ start, unsigned short* __restrict__ y)
{
    __shared__ __align__(16) unsigned short Asm[TMM * BK];
    __shared__ __align__(16) unsigned short Bsm[TNN * BK];

    int row0 = blockIdx.y * TMM;
    int tot = start[E_];
    if (row0 >= tot) return;
    int e = 0;
    while (e < E_ - 1 && row0 >= start[e + 1]) ++e;

    int nblk = blockIdx.x & 3, ck = blockIdx.x >> 2;
    int n0 = nblk * TNN;
    const unsigned short* Ag = h + (size_t)row0 * H_;
    const unsigned short* Bg = w2t + (size_t)e * D_ * H_ + (size_t)n0 * H_;

    int tid = threadIdx.x;
    int wid = tid >> 6, lane = tid & 63;
    int wm = wid & 1, wn = wid >> 1;
    int quad = lane >> 4, r16 = lane & 15;
    int srow = lane >> 3;
    int scol = ((lane & 7) ^ srow) * 8;
    int rsw = r16 & 7;

    floatx4 acc[4][4];
#pragma unroll
    for (int i = 0; i < 4; ++i)
#pragma unroll
        for (int j = 0; j < 4; ++j) acc[i][j] = (floatx4){0.f, 0.f, 0.f, 0.f};

    const int KITERS = H_ / BK / CK;           // 32
    int kbase = ck * KITERS;
    for (int kc = kbase; kc < kbase + KITERS; ++kc) {
        int k0 = kc * BK;
#pragma unroll
        for (int q = 0; q < 2; ++q) {
            int rb = wid * 16 + q * 8;
            GLP16(Ag + (size_t)(rb + srow) * H_ + k0 + scol, Asm + rb * BK);
        }
#pragma unroll
        for (int q = 0; q < 4; ++q) {
            int rb = wid * 32 + q * 8;
            GLP16(Bg + (size_t)(rb + srow) * H_ + k0 + scol, Bsm + rb * BK);
        }
        __syncthreads();
#pragma unroll
        for (int ks = 0; ks < 2; ++ks) {
            short8 af[4], bfr[4];
#pragma unroll
            for (int i = 0; i < 4; ++i)
                af[i] = *(const short8*)(Asm + (wm * 64 + i * 16 + r16) * BK + ((ks * 4 + quad) ^ rsw) * 8);
#pragma unroll
            for (int j = 0; j < 4; ++j)
                bfr[j] = *(const short8*)(Bsm + (wn * 64 + j * 16 + r16) * BK + ((ks * 4 + quad) ^ rsw) * 8);
#pragma unroll
            for (int i = 0; i < 4; ++i)
#pragma unroll
                for (int j = 0; j < 4; ++j)
                    acc[i][j] = __builtin_amdgcn_mfma_f32_16x16x32_bf16(af[i], bfr[j], acc[i][j], 0, 0, 0);
        }
        __syncthreads();
    }

    unsigned short* ys = y + (size_t)ck * CAP * D_;
#pragma unroll
    for (int i = 0; i < 4; ++i) {
#pragma unroll
        for (int r = 0; r < 4; ++r) {
            int row = row0 + wm * 64 + i * 16 + quad * 4 + r;
            unsigned short* op = ys + (size_t)row * D_ + n0 + wn * 64 + r16;
#pragma unroll
            for (int j = 0; j < 4; ++j)
                op[j * 16] = f2bf(acc[i][j][r]);
        }
    }
}

// ---------------- Combine: out[t] = sum_k w_k * (sum_s y_s[row_k] + b2[e_k]) ----------------
__global__ __launch_bounds__(256) void combine_kernel(
    const unsigned short* __restrict__ y, const int* __restrict__ start,
    const int2* __restrict__ inv_ei, const float2* __restrict__ inv_w,
    const float* __restrict__ b2, float* __restrict__ out)
{
    int t = blockIdx.x;
    int tid = threadIdx.x;       // 256 threads x 4 floats = D_
    int2 ei = inv_ei[t];
    float2 w = inv_w[t];
    int e1 = ei.x & 7, x1 = ei.x >> 3;
    int e2 = ei.y & 7, x2 = ei.y >> 3;
    size_t r1 = (size_t)start[e1] + x1;
    size_t r2 = (size_t)start[e2] + x2;
    const size_t SL = (size_t)CAP * D_;
    ushort4 a0 = ((const ushort4*)(y + r1 * D_))[tid];
    ushort4 a1 = ((const ushort4*)(y + SL + r1 * D_))[tid];
    ushort4 c0 = ((const ushort4*)(y + r2 * D_))[tid];
    ushort4 c1 = ((const ushort4*)(y + SL + r2 * D_))[tid];
    float4 bA = ((const float4*)(b2 + (size_t)e1 * D_))[tid];
    float4 bB = ((const float4*)(b2 + (size_t)e2 * D_))[tid];
    float4 o;
    o.x = w.x * (bf2f(a0.x) + bf2f(a1.x) + bA.x) + w.y * (bf2f(c0.x) + bf2f(c1.x) + bB.x);
    o.y = w.x * (bf2f(a0.y) + bf2f(a1.y) + bA.y) + w.y * (bf2f(c0.y) + bf2f(c1.y) + bB.y);
    o.z = w.x * (bf2f(a0.z) + bf2f(a1.z) + bA.z) + w.y * (bf2f(c0.z) + bf2f(c1.z) + bB.z);
    o.w = w.x * (bf2f(a0.w) + bf2f(a1.w) + bA.w) + w.y * (bf2f(c0.w) + bf2f(c1.w) + bB.w);
    ((float4*)(out + (size_t)t * D_))[tid] = o;
}

// ---------------- Launch ----------------
extern "C" void kernel_launch(void* const* d_in, const int* in_sizes, int n_in,
                              void* d_out, int out_size, void* d_ws, size_t ws_size,
                              hipStream_t stream)
{
    const float* x  = (const float*)d_in[0];
    const float* Wr = (const float*)d_in[1];
    const float* W1 = (const float*)d_in[2];
    const float* b1 = (const float*)d_in[3];
    const float* W2 = (const float*)d_in[4];
    const float* b2 = (const float*)d_in[5];
    float* out = (float*)d_out;

    // ws layout (~313 MB)
    char* ws = (char*)d_ws;
    int*    cnt      = (int*)ws;                    // 32 B
    int*    start    = (int*)(ws + 64);             // 36 B
    int*    tok_list = (int*)(ws + 256);            // 256 KiB
    int2*   inv_ei   = (int2*)(ws + 393216);        // 64 KiB
    float2* inv_w    = (float2*)(ws + 458752);      // 64 KiB
    char* p0 = ws + (1u << 20);
    unsigned short* xg  = (unsigned short*)p0;                                  // 35.65 MB
    unsigned short* w1t = (unsigned short*)(p0 + 35651584ull);                  // 67.1 MB
    unsigned short* h   = (unsigned short*)(p0 + 35651584ull + 67108864ull);    // 142.6 MB
    unsigned short* w2t = (unsigned short*)(p0 + 35651584ull + 67108864ull + 142606336ull); // 67.1 MB
    // y aliases xg+w1t (both dead after fc1): 2 slices x 35.65 MB = 71.3 MB <= 102.8 MB
    unsigned short* y   = (unsigned short*)p0;
    (void)ws_size; (void)in_sizes; (void)n_in; (void)out_size;

    hipMemsetAsync(ws, 0, 64, stream);   // zero cnt

    transpose_cvt<<<dim3(64, 16, 16), 256, 0, stream>>>(W1, W2, w1t, w2t);
    router_kernel<<<T_ / 4, 256, 0, stream>>>(x, Wr, cnt, tok_list, inv_ei, inv_w);
    offsets_kernel<<<1, 64, 0, stream>>>(cnt, start);
    gather_kernel<<<CAP, 256, 0, stream>>>(x, cnt, start, tok_list, xg);
    fc1_kernel<<<dim3(H_ / TNN, NBY), 512, 0, stream>>>(xg, w1t, b1, start, h);
    fc2_kernel<<<dim3((D_ / TNN) * CK, NBY), 512, 0, stream>>>(h, w2t, start, y);
    combine_kernel<<<T_, 256, 0, stream>>>(y, start, inv_ei, inv_w, b2, out);
}